// Round 5
// baseline (225.678 us; speedup 1.0000x reference)
//
#include <hip/hip_runtime.h>
#include <hip/hip_bf16.h>

#define T_N 500000
#define NTILE 31250          // T_N / 16 rows per wave-tile (exact)
#define NBLK 768             // persistent blocks (3/CU)
#define NWAVES (NBLK * 4)    // wave stride over tiles
#define NCHUNK 4096
#define CHUNKL 128
#define NPART 1024

typedef __attribute__((ext_vector_type(8))) short short8v;
typedef __attribute__((ext_vector_type(4))) float float4v;

__device__ __forceinline__ short f2bf(float f) {
    __hip_bfloat16 b = __float2bfloat16(f);
    return *reinterpret_cast<short*>(&b);
}

__device__ __forceinline__ short8v cvt8(const float4 a, const float4 b) {
    short8v r;
    r[0] = f2bf(a.x); r[1] = f2bf(a.y); r[2] = f2bf(a.z); r[3] = f2bf(a.w);
    r[4] = f2bf(b.x); r[5] = f2bf(b.y); r[6] = f2bf(b.z); r[7] = f2bf(b.w);
    return r;
}

// packed B-fragment base indices (each frag = 64 lanes x 8 bf16 = 1KB)
#define FC1 0    // critic W1: 4 k-steps x 4 col-tiles
#define FA1 16   // actor  W1
#define FC2 32   // critic W2: 2 k-steps x 4 col-tiles
#define FA2 40   // actor  W2
#define FA3 48   // actor  W3: 2 k-steps x 1 col-tile (16 actions)
#define NFRAG 50

// ---- weight pre-pack: B-frag slot (g=lane>>4, j) <-> k = s*32 + g*8 + j ----
__global__ __launch_bounds__(64) void k_pack(
    const float* __restrict__ cW1, const float* __restrict__ aW1,
    const float* __restrict__ cW2, const float* __restrict__ aW2,
    const float* __restrict__ aW3, short8v* __restrict__ packed)
{
    const int f = blockIdx.x, l = threadIdx.x;
    const int g = l >> 4, col = l & 15;
    const float* W; int s, c, ncol;
    if (f < FA1)      { W = cW1; s = f >> 2;         c = f & 3;         ncol = 64; }
    else if (f < FC2) { W = aW1; s = (f - FA1) >> 2; c = (f - FA1) & 3; ncol = 64; }
    else if (f < FA2) { W = cW2; s = (f - FC2) >> 2; c = (f - FC2) & 3; ncol = 64; }
    else if (f < FA3) { W = aW2; s = (f - FA2) >> 2; c = (f - FA2) & 3; ncol = 64; }
    else              { W = aW3; s = f - FA3;        c = 0;             ncol = 16; }
    short8v frag;
    #pragma unroll
    for (int j = 0; j < 8; ++j) {
        int k = s * 32 + g * 8 + j;
        frag[j] = f2bf(W[k * ncol + c * 16 + col]);
    }
    packed[f * 64 + l] = frag;
}

__device__ __forceinline__ void store_h(short (*hb)[68], const float4v* acc, int g, int q) {
    #pragma unroll
    for (int c = 0; c < 4; ++c)
        #pragma unroll
        for (int r = 0; r < 4; ++r)
            hb[g * 4 + r][c * 16 + q] = f2bf(fmaxf(acc[c][r], 0.f));
}

// ---- persistent fused MLP: 4 waves/block, grid-stride over 16-row tiles ----
__global__ __launch_bounds__(256) void k_mlp(
    const float* __restrict__ states, const float* __restrict__ next_states,
    const float* __restrict__ rewards, const float* __restrict__ dones,
    const int* __restrict__ actions, const float* __restrict__ old_logp,
    const short8v* __restrict__ pk,
    const float* __restrict__ cb1, const float* __restrict__ ab1,
    const float* __restrict__ cb2, const float* __restrict__ ab2,
    const float* __restrict__ ab3,
    const float* __restrict__ cW3, const float* __restrict__ cb3,
    float* __restrict__ delta_o, float* __restrict__ coef_o,
    float* __restrict__ ratio_o, float* __restrict__ ent_o)
{
    __shared__ __align__(16) short hlds[4][2][16][68];
    const int wv = threadIdx.x >> 6, l = threadIdx.x & 63;
    const int g = l >> 4, q = l & 15;
    short (*h0)[68] = hlds[wv][0];
    short (*h1)[68] = hlds[wv][1];

    int tile = blockIdx.x * 4 + wv;
    if (tile >= NTILE) return;

    // ---- preload tile 0's x rows (32 dwordx4 in flight) ----
    float4 rs[8], rn[8];
    {
        const float* xs = states + ((long long)tile * 16 + q) * 128 + g * 8;
        const float* xn = next_states + ((long long)tile * 16 + q) * 128 + g * 8;
        #pragma unroll
        for (int s = 0; s < 4; ++s) {
            rs[2 * s]     = *reinterpret_cast<const float4*>(xs + s * 32);
            rs[2 * s + 1] = *reinterpret_cast<const float4*>(xs + s * 32 + 4);
            rn[2 * s]     = *reinterpret_cast<const float4*>(xn + s * 32);
            rn[2 * s + 1] = *reinterpret_cast<const float4*>(xn + s * 32 + 4);
        }
    }

    while (true) {
        const int next = tile + NWAVES;
        const long long r0 = (long long)tile * 16;

        // ---- convert current raws to MFMA A-frags (raws die here) ----
        short8v sa[4], na[4];
        #pragma unroll
        for (int s = 0; s < 4; ++s) {
            sa[s] = cvt8(rs[2 * s], rs[2 * s + 1]);
            na[s] = cvt8(rn[2 * s], rn[2 * s + 1]);
        }

        // ---- issue next tile's loads NOW; they complete under compute ----
        if (next < NTILE) {
            const float* xs = states + ((long long)next * 16 + q) * 128 + g * 8;
            const float* xn = next_states + ((long long)next * 16 + q) * 128 + g * 8;
            #pragma unroll
            for (int s = 0; s < 4; ++s) {
                rs[2 * s]     = *reinterpret_cast<const float4*>(xs + s * 32);
                rs[2 * s + 1] = *reinterpret_cast<const float4*>(xs + s * 32 + 4);
                rn[2 * s]     = *reinterpret_cast<const float4*>(xn + s * 32);
                rn[2 * s + 1] = *reinterpret_cast<const float4*>(xn + s * 32 + 4);
            }
        }

        // ===== critic L1: states + next share each weight frag =====
        float4v accC[4], accN[4];
        #pragma unroll
        for (int c = 0; c < 4; ++c) {
            float b = cb1[c * 16 + q];
            accC[c] = (float4v){b, b, b, b};
            accN[c] = accC[c];
        }
        #pragma unroll
        for (int s = 0; s < 4; ++s) {
            #pragma unroll
            for (int c = 0; c < 4; ++c) {
                short8v w = pk[(FC1 + s * 4 + c) * 64 + l];
                accC[c] = __builtin_amdgcn_mfma_f32_16x16x32_bf16(sa[s], w, accC[c], 0, 0, 0);
                accN[c] = __builtin_amdgcn_mfma_f32_16x16x32_bf16(na[s], w, accN[c], 0, 0, 0);
            }
        }
        store_h(h0, accC, g, q);
        store_h(h1, accN, g, q);

        // ===== critic L2 (both) + linear head =====
        float4v c2C[4], c2N[4];
        #pragma unroll
        for (int c = 0; c < 4; ++c) {
            float b = cb2[c * 16 + q];
            c2C[c] = (float4v){b, b, b, b};
            c2N[c] = c2C[c];
        }
        #pragma unroll
        for (int s = 0; s < 2; ++s) {
            short8v aC = *reinterpret_cast<const short8v*>(&h0[q][s * 32 + g * 8]);
            short8v aN = *reinterpret_cast<const short8v*>(&h1[q][s * 32 + g * 8]);
            #pragma unroll
            for (int c = 0; c < 4; ++c) {
                short8v w = pk[(FC2 + s * 4 + c) * 64 + l];
                c2C[c] = __builtin_amdgcn_mfma_f32_16x16x32_bf16(aC, w, c2C[c], 0, 0, 0);
                c2N[c] = __builtin_amdgcn_mfma_f32_16x16x32_bf16(aN, w, c2N[c], 0, 0, 0);
            }
        }
        float vr[4] = {0.f, 0.f, 0.f, 0.f}, nr[4] = {0.f, 0.f, 0.f, 0.f};
        #pragma unroll
        for (int c = 0; c < 4; ++c) {
            float w3 = cW3[c * 16 + q];
            #pragma unroll
            for (int r = 0; r < 4; ++r) {
                vr[r] = fmaf(fmaxf(c2C[c][r], 0.f), w3, vr[r]);
                nr[r] = fmaf(fmaxf(c2N[c][r], 0.f), w3, nr[r]);
            }
        }
        #pragma unroll
        for (int o = 1; o < 16; o <<= 1)
            #pragma unroll
            for (int r = 0; r < 4; ++r) {
                vr[r] += __shfl_xor(vr[r], o);
                nr[r] += __shfl_xor(nr[r], o);
            }
        const float cb3v = cb3[0];
        float v[4], nv[4];
        #pragma unroll
        for (int r = 0; r < 4; ++r) { v[r] = vr[r] + cb3v; nv[r] = nr[r] + cb3v; }

        // ===== actor L1 / L2 / L3 =====
        float4v aA[4];
        #pragma unroll
        for (int c = 0; c < 4; ++c) { float b = ab1[c * 16 + q]; aA[c] = (float4v){b, b, b, b}; }
        #pragma unroll
        for (int s = 0; s < 4; ++s)
            #pragma unroll
            for (int c = 0; c < 4; ++c)
                aA[c] = __builtin_amdgcn_mfma_f32_16x16x32_bf16(sa[s], pk[(FA1 + s * 4 + c) * 64 + l], aA[c], 0, 0, 0);
        store_h(h0, aA, g, q);

        float4v a2[4];
        #pragma unroll
        for (int c = 0; c < 4; ++c) { float b = ab2[c * 16 + q]; a2[c] = (float4v){b, b, b, b}; }
        #pragma unroll
        for (int s = 0; s < 2; ++s) {
            short8v aa = *reinterpret_cast<const short8v*>(&h0[q][s * 32 + g * 8]);
            #pragma unroll
            for (int c = 0; c < 4; ++c)
                a2[c] = __builtin_amdgcn_mfma_f32_16x16x32_bf16(aa, pk[(FA2 + s * 4 + c) * 64 + l], a2[c], 0, 0, 0);
        }
        store_h(h1, a2, g, q);

        const float b3 = ab3[q];
        float4v a3 = (float4v){b3, b3, b3, b3};
        #pragma unroll
        for (int s = 0; s < 2; ++s) {
            short8v aa = *reinterpret_cast<const short8v*>(&h1[q][s * 32 + g * 8]);
            a3 = __builtin_amdgcn_mfma_f32_16x16x32_bf16(aa, pk[(FA3 + s) * 64 + l], a3, 0, 0, 0);
        }

        // ===== softmax over the 16 lanes of each group (action = q) =====
        float lg[4], mx[4], pe[4], se[4], tt[4], ent[4], logp[4];
        #pragma unroll
        for (int r = 0; r < 4; ++r) { lg[r] = a3[r]; mx[r] = lg[r]; }
        #pragma unroll
        for (int o = 1; o < 16; o <<= 1)
            #pragma unroll
            for (int r = 0; r < 4; ++r) mx[r] = fmaxf(mx[r], __shfl_xor(mx[r], o));
        #pragma unroll
        for (int r = 0; r < 4; ++r) {
            pe[r] = __expf(lg[r] - mx[r]);
            se[r] = pe[r];
            tt[r] = pe[r] * lg[r];
        }
        #pragma unroll
        for (int o = 1; o < 16; o <<= 1)
            #pragma unroll
            for (int r = 0; r < 4; ++r) {
                se[r] += __shfl_xor(se[r], o);
                tt[r] += __shfl_xor(tt[r], o);
            }
        const int4 av = *reinterpret_cast<const int4*>(&actions[r0 + g * 4]);
        const int act[4] = {av.x, av.y, av.z, av.w};
        #pragma unroll
        for (int r = 0; r < 4; ++r) {
            float ls = __logf(se[r]);
            ent[r] = mx[r] + ls - tt[r] / se[r];        // == -sum p*log p
            float sel = __shfl(lg[r], (l & 48) | act[r]);
            logp[r] = sel - mx[r] - ls;
        }

        // ===== epilogue: lane q==0 of each group writes its 4 rows =====
        if (q == 0) {
            const long long rb = r0 + g * 4;
            const float4 rw = *reinterpret_cast<const float4*>(&rewards[rb]);
            const float4 dn = *reinterpret_cast<const float4*>(&dones[rb]);
            const float4 ol = *reinterpret_cast<const float4*>(&old_logp[rb]);
            const float rwv[4] = {rw.x, rw.y, rw.z, rw.w};
            const float dnv[4] = {dn.x, dn.y, dn.z, dn.w};
            const float olv[4] = {ol.x, ol.y, ol.z, ol.w};
            const float GL = 0.99f * 0.95f;
            float dl[4], cf[4], rt[4];
            #pragma unroll
            for (int r = 0; r < 4; ++r) {
                float nd = 1.f - dnv[r];
                dl[r] = fmaf(0.99f * nd, nv[r], rwv[r]) - v[r];
                cf[r] = GL * nd;
                rt[r] = __expf(logp[r] - olv[r]);
            }
            float4 t;
            t.x = dl[0]; t.y = dl[1]; t.z = dl[2]; t.w = dl[3];
            *reinterpret_cast<float4*>(&delta_o[rb]) = t;
            t.x = cf[0]; t.y = cf[1]; t.z = cf[2]; t.w = cf[3];
            *reinterpret_cast<float4*>(&coef_o[rb]) = t;
            t.x = rt[0]; t.y = rt[1]; t.z = rt[2]; t.w = rt[3];
            *reinterpret_cast<float4*>(&ratio_o[rb]) = t;
            t.x = ent[0]; t.y = ent[1]; t.z = ent[2]; t.w = ent[3];
            *reinterpret_cast<float4*>(&ent_o[rb]) = t;
        }

        if (next >= NTILE) break;
        tile = next;
    }
}

// ---------------- GAE: chunk transforms ----------------
__global__ __launch_bounds__(256) void k_gae_chunk(
    const float* __restrict__ coef, const float* __restrict__ delta,
    float* __restrict__ P, float* __restrict__ Q)
{
    const int c = blockIdx.x * 256 + threadIdx.x;
    const long long lo = (long long)c * CHUNKL;
    float p = 1.f, a = 0.f;
    if (lo < T_N) {
        const int n = (int)((T_N - lo < CHUNKL) ? (T_N - lo) : CHUNKL);
        for (int j = (n >> 2) - 1; j >= 0; --j) {
            float4 cfv = *reinterpret_cast<const float4*>(&coef[lo + 4 * j]);
            float4 dlv = *reinterpret_cast<const float4*>(&delta[lo + 4 * j]);
            a = fmaf(cfv.w, a, dlv.w);
            a = fmaf(cfv.z, a, dlv.z);
            a = fmaf(cfv.y, a, dlv.y);
            a = fmaf(cfv.x, a, dlv.x);
            p *= cfv.x * cfv.y * cfv.z * cfv.w;
        }
    }
    P[c] = p; Q[c] = a;
}

// suffix scan of 4096 chunk transforms in one block (4 per thread)
__global__ __launch_bounds__(1024) void k_gae_scan(
    const float* __restrict__ P, const float* __restrict__ Q,
    float* __restrict__ carry)
{
    __shared__ float sp[1024], sq[1024];
    const int t = threadIdx.x, b = t * 4;
    float p = P[b + 3], q = Q[b + 3];
    #pragma unroll
    for (int c = 2; c >= 0; --c) {
        float pc = P[b + c], qc = Q[b + c];
        q = fmaf(pc, q, qc);
        p = pc * p;
    }
    sp[t] = p; sq[t] = q;
    __syncthreads();
    for (int d = 1; d < 1024; d <<= 1) {
        float pp = sp[t], qq = sq[t];
        float p2 = 1.f, q2 = 0.f;
        const bool has = (t + d) < 1024;
        if (has) { p2 = sp[t + d]; q2 = sq[t + d]; }
        __syncthreads();
        if (has) { sp[t] = pp * p2; sq[t] = fmaf(pp, q2, qq); }
        __syncthreads();
    }
    float x = (t + 1 < 1024) ? sq[t + 1] : 0.f;
    #pragma unroll
    for (int c = 3; c >= 0; --c) {
        carry[b + c] = x;
        x = fmaf(P[b + c], x, Q[b + c]);
    }
}

// apply carries, write adv, fused sum/sum^2 partials
__global__ __launch_bounds__(256) void k_gae_apply(
    const float* __restrict__ coef, const float* __restrict__ delta,
    const float* __restrict__ carry, float* __restrict__ adv,
    float* __restrict__ part)
{
    const int c = blockIdx.x * 256 + threadIdx.x;
    const long long lo = (long long)c * CHUNKL;
    float s = 0.f, s2 = 0.f;
    if (lo < T_N) {
        const int n = (int)((T_N - lo < CHUNKL) ? (T_N - lo) : CHUNKL);
        float a = carry[c];
        for (int j = (n >> 2) - 1; j >= 0; --j) {
            float4 cfv = *reinterpret_cast<const float4*>(&coef[lo + 4 * j]);
            float4 dlv = *reinterpret_cast<const float4*>(&delta[lo + 4 * j]);
            float a3 = fmaf(cfv.w, a, dlv.w);
            float a2v = fmaf(cfv.z, a3, dlv.z);
            float a1 = fmaf(cfv.y, a2v, dlv.y);
            float a0 = fmaf(cfv.x, a1, dlv.x);
            float4 o; o.x = a0; o.y = a1; o.z = a2v; o.w = a3;
            *reinterpret_cast<float4*>(&adv[lo + 4 * j]) = o;
            a = a0;
            s += a0 + a1 + a2v + a3;
            s2 += a0 * a0 + a1 * a1 + a2v * a2v + a3 * a3;
        }
    }
    #pragma unroll
    for (int o = 32; o > 0; o >>= 1) { s += __shfl_down(s, o); s2 += __shfl_down(s2, o); }
    __shared__ float l0[4], l1[4];
    const int wv = threadIdx.x >> 6, ln = threadIdx.x & 63;
    if (ln == 0) { l0[wv] = s; l1[wv] = s2; }
    __syncthreads();
    if (threadIdx.x == 0) {
        part[blockIdx.x * 2]     = l0[0] + l0[1] + l0[2] + l0[3];
        part[blockIdx.x * 2 + 1] = l1[0] + l1[1] + l1[2] + l1[3];
    }
}

// actor surrogate + entropy reduction
__global__ __launch_bounds__(256) void k_actor(
    const float* __restrict__ adv, const float* __restrict__ ratio,
    const float* __restrict__ ent, const float* __restrict__ part,
    float* __restrict__ part4)
{
    __shared__ float st[2];
    if (threadIdx.x == 0) {
        float S = 0.f, S2 = 0.f;
        #pragma unroll
        for (int i = 0; i < 16; ++i) { S += part[2 * i]; S2 += part[2 * i + 1]; }
        const float Tf = (float)T_N;
        float mean = S / Tf;
        float var = (S2 - S * S / Tf) / (Tf - 1.f);
        st[0] = mean;
        st[1] = 1.f / (sqrtf(fmaxf(var, 0.f)) + 1e-8f);
    }
    __syncthreads();
    const float mean = st[0], isd = st[1];
    float sm = 0.f, se = 0.f;
    for (long long i = (long long)blockIdx.x * 256 + threadIdx.x; i < T_N;
         i += (long long)gridDim.x * 256) {
        float an = (adv[i] - mean) * isd;
        float rt = ratio[i];
        float s1 = rt * an;
        float s2v = fminf(fmaxf(rt, 0.8f), 1.2f) * an;
        sm += fminf(s1, s2v);
        se += ent[i];
    }
    #pragma unroll
    for (int o = 32; o > 0; o >>= 1) { sm += __shfl_down(sm, o); se += __shfl_down(se, o); }
    __shared__ float l0[4], l1[4];
    const int wv = threadIdx.x >> 6, ln = threadIdx.x & 63;
    if (ln == 0) { l0[wv] = sm; l1[wv] = se; }
    __syncthreads();
    if (threadIdx.x == 0) {
        part4[blockIdx.x * 2]     = l0[0] + l0[1] + l0[2] + l0[3];
        part4[blockIdx.x * 2 + 1] = l1[0] + l1[1] + l1[2] + l1[3];
    }
}

__global__ __launch_bounds__(1024) void k_final(
    const float* __restrict__ part4, const float* __restrict__ part,
    float* __restrict__ out)
{
    const int t = threadIdx.x;
    float sm = part4[t * 2], se = part4[t * 2 + 1];
    #pragma unroll
    for (int o = 32; o > 0; o >>= 1) { sm += __shfl_down(sm, o); se += __shfl_down(se, o); }
    __shared__ float l0[16], l1[16];
    const int wv = t >> 6, ln = t & 63;
    if (ln == 0) { l0[wv] = sm; l1[wv] = se; }
    __syncthreads();
    if (t == 0) {
        float SM = 0.f, SE = 0.f;
        #pragma unroll
        for (int i = 0; i < 16; ++i) { SM += l0[i]; SE += l1[i]; }
        float S2 = 0.f;
        #pragma unroll
        for (int i = 0; i < 16; ++i) S2 += part[2 * i + 1];
        const float Tf = (float)T_N;
        float actor_loss = -SM / Tf;
        float ent_loss = SE / Tf;
        float critic_loss = S2 / Tf;     // mean(adv^2) == mean((v-returns)^2)
        float total = actor_loss + 0.5f * critic_loss - 0.01f * ent_loss;
        out[0] = total; out[1] = actor_loss; out[2] = critic_loss; out[3] = ent_loss;
    }
}

extern "C" void kernel_launch(void* const* d_in, const int* in_sizes, int n_in,
                              void* d_out, int out_size, void* d_ws, size_t ws_size,
                              hipStream_t stream) {
    (void)in_sizes; (void)n_in; (void)out_size; (void)ws_size;
    const float* states      = (const float*)d_in[0];
    const float* next_states = (const float*)d_in[1];
    const float* rewards     = (const float*)d_in[2];
    const float* dones       = (const float*)d_in[3];
    const int*   actions     = (const int*)d_in[4];
    const float* old_logp    = (const float*)d_in[5];
    const float* aW1 = (const float*)d_in[6];  const float* ab1 = (const float*)d_in[7];
    const float* aW2 = (const float*)d_in[8];  const float* ab2 = (const float*)d_in[9];
    const float* aW3 = (const float*)d_in[10]; const float* ab3 = (const float*)d_in[11];
    const float* cW1 = (const float*)d_in[12]; const float* cb1 = (const float*)d_in[13];
    const float* cW2 = (const float*)d_in[14]; const float* cb2 = (const float*)d_in[15];
    const float* cW3 = (const float*)d_in[16]; const float* cb3 = (const float*)d_in[17];
    float* out = (float*)d_out;

    float* ws = (float*)d_ws;
    float* delta = ws;                      // T
    float* coef  = ws + 1 * (size_t)T_N;    // T
    float* ratio = ws + 2 * (size_t)T_N;    // T
    float* entb  = ws + 3 * (size_t)T_N;    // T
    float* adv   = ws + 4 * (size_t)T_N;    // T
    float* P     = ws + 5 * (size_t)T_N;    // 4096
    float* Q     = P + NCHUNK;              // 4096
    float* carry = Q + NCHUNK;              // 4096
    float* part  = carry + NCHUNK;          // 32
    float* part4 = part + 32;               // 2048
    short8v* packed = (short8v*)(part4 + 2048);  // 50KB, 16B-aligned offset

    k_pack<<<NFRAG, 64, 0, stream>>>(cW1, aW1, cW2, aW2, aW3, packed);
    k_mlp<<<NBLK, 256, 0, stream>>>(
        states, next_states, rewards, dones, actions, old_logp, packed,
        cb1, ab1, cb2, ab2, ab3, cW3, cb3, delta, coef, ratio, entb);
    k_gae_chunk<<<NCHUNK / 256, 256, 0, stream>>>(coef, delta, P, Q);
    k_gae_scan<<<1, 1024, 0, stream>>>(P, Q, carry);
    k_gae_apply<<<NCHUNK / 256, 256, 0, stream>>>(coef, delta, carry, adv, part);
    k_actor<<<NPART, 256, 0, stream>>>(adv, ratio, entb, part, part4);
    k_final<<<1, 1024, 0, stream>>>(part4, part, out);
}

// Round 6
// 211.781 us; speedup vs baseline: 1.0656x; 1.0656x over previous
//
#include <hip/hip_runtime.h>
#include <hip/hip_bf16.h>

#define T_N 500000
#define NTILE 31250          // T_N / 16 rows per wave-tile (exact)
#define NBLK 512             // persistent blocks (exactly 2/CU at 68.6KB LDS)
#define NWAVES (NBLK * 4)    // wave stride over tiles
#define NCHUNK 4096
#define CHUNKL 128
#define NPART 1024

typedef __attribute__((ext_vector_type(8))) short short8v;
typedef __attribute__((ext_vector_type(4))) float float4v;

__device__ __forceinline__ short f2bf(float f) {
    __hip_bfloat16 b = __float2bfloat16(f);
    return *reinterpret_cast<short*>(&b);
}

__device__ __forceinline__ short8v cvt8(const float4 a, const float4 b) {
    short8v r;
    r[0] = f2bf(a.x); r[1] = f2bf(a.y); r[2] = f2bf(a.z); r[3] = f2bf(a.w);
    r[4] = f2bf(b.x); r[5] = f2bf(b.y); r[6] = f2bf(b.z); r[7] = f2bf(b.w);
    return r;
}

// packed B-fragment base indices (each frag = 64 lanes x 8 bf16 = 1KB)
#define FC1 0    // critic W1: 4 k-steps x 4 col-tiles
#define FA1 16   // actor  W1
#define FC2 32   // critic W2: 2 k-steps x 4 col-tiles
#define FA2 40   // actor  W2
#define FA3 48   // actor  W3: 2 k-steps x 1 col-tile (16 actions)
#define NFRAG 50

// ---- weight pre-pack: B-frag slot (g=lane>>4, j) <-> k = s*32 + g*8 + j ----
__global__ __launch_bounds__(64) void k_pack(
    const float* __restrict__ cW1, const float* __restrict__ aW1,
    const float* __restrict__ cW2, const float* __restrict__ aW2,
    const float* __restrict__ aW3, short8v* __restrict__ packed)
{
    const int f = blockIdx.x, l = threadIdx.x;
    const int g = l >> 4, col = l & 15;
    const float* W; int s, c, ncol;
    if (f < FA1)      { W = cW1; s = f >> 2;         c = f & 3;         ncol = 64; }
    else if (f < FC2) { W = aW1; s = (f - FA1) >> 2; c = (f - FA1) & 3; ncol = 64; }
    else if (f < FA2) { W = cW2; s = (f - FC2) >> 2; c = (f - FC2) & 3; ncol = 64; }
    else if (f < FA3) { W = aW2; s = (f - FA2) >> 2; c = (f - FA2) & 3; ncol = 64; }
    else              { W = aW3; s = f - FA3;        c = 0;             ncol = 16; }
    short8v frag;
    #pragma unroll
    for (int j = 0; j < 8; ++j) {
        int k = s * 32 + g * 8 + j;
        frag[j] = f2bf(W[k * ncol + c * 16 + col]);
    }
    packed[f * 64 + l] = frag;
}

__device__ __forceinline__ void store_h(short (*hb)[68], const float4v* acc, int g, int q) {
    #pragma unroll
    for (int c = 0; c < 4; ++c)
        #pragma unroll
        for (int r = 0; r < 4; ++r)
            hb[g * 4 + r][c * 16 + q] = f2bf(fmaxf(acc[c][r], 0.f));
}

// ---- persistent fused MLP: 4 waves/block; weights staged in LDS ----
__global__ __launch_bounds__(256) void k_mlp(
    const float* __restrict__ states, const float* __restrict__ next_states,
    const float* __restrict__ rewards, const float* __restrict__ dones,
    const int* __restrict__ actions, const float* __restrict__ old_logp,
    const short8v* __restrict__ pk,
    const float* __restrict__ cb1, const float* __restrict__ ab1,
    const float* __restrict__ cb2, const float* __restrict__ ab2,
    const float* __restrict__ ab3,
    const float* __restrict__ cW3, const float* __restrict__ cb3,
    float* __restrict__ delta_o, float* __restrict__ coef_o,
    float* __restrict__ ratio_o, float* __restrict__ ent_o)
{
    __shared__ __align__(16) short8v spk[NFRAG * 64];     // 51.2 KB weights
    __shared__ __align__(16) short hlds[4][2][16][68];    // 17.4 KB h buffers
    const int wv = threadIdx.x >> 6, l = threadIdx.x & 63;
    const int g = l >> 4, q = l & 15;
    short (*h0)[68] = hlds[wv][0];
    short (*h1)[68] = hlds[wv][1];

    // ---- stage all weight fragments into LDS once per block ----
    for (int i = threadIdx.x; i < NFRAG * 64; i += 256) spk[i] = pk[i];
    __syncthreads();                                       // only barrier

    int tile = blockIdx.x * 4 + wv;
    if (tile >= NTILE) return;

    // ---- tile-invariant per-lane constants (hoisted out of loop) ----
    float bc1[4], bc2[4], ba1[4], ba2[4], w3[4];
    #pragma unroll
    for (int c = 0; c < 4; ++c) {
        bc1[c] = cb1[c * 16 + q];
        bc2[c] = cb2[c * 16 + q];
        ba1[c] = ab1[c * 16 + q];
        ba2[c] = ab2[c * 16 + q];
        w3[c]  = cW3[c * 16 + q];
    }
    const float ab3q = ab3[q];
    const float cb3v = cb3[0];

    // ---- preload tile 0's x rows ----
    float4 rs[8], rn[8];
    {
        const float* xs = states + ((long long)tile * 16 + q) * 128 + g * 8;
        const float* xn = next_states + ((long long)tile * 16 + q) * 128 + g * 8;
        #pragma unroll
        for (int s = 0; s < 4; ++s) {
            rs[2 * s]     = *reinterpret_cast<const float4*>(xs + s * 32);
            rs[2 * s + 1] = *reinterpret_cast<const float4*>(xs + s * 32 + 4);
            rn[2 * s]     = *reinterpret_cast<const float4*>(xn + s * 32);
            rn[2 * s + 1] = *reinterpret_cast<const float4*>(xn + s * 32 + 4);
        }
    }

    while (true) {
        const int next = tile + NWAVES;
        const long long r0 = (long long)tile * 16;

        // ---- convert current raws to MFMA A-frags (raws die here) ----
        short8v sa[4], na[4];
        #pragma unroll
        for (int s = 0; s < 4; ++s) {
            sa[s] = cvt8(rs[2 * s], rs[2 * s + 1]);
            na[s] = cvt8(rn[2 * s], rn[2 * s + 1]);
        }

        // ---- issue next tile's loads NOW; they complete under compute ----
        if (next < NTILE) {
            const float* xs = states + ((long long)next * 16 + q) * 128 + g * 8;
            const float* xn = next_states + ((long long)next * 16 + q) * 128 + g * 8;
            #pragma unroll
            for (int s = 0; s < 4; ++s) {
                rs[2 * s]     = *reinterpret_cast<const float4*>(xs + s * 32);
                rs[2 * s + 1] = *reinterpret_cast<const float4*>(xs + s * 32 + 4);
                rn[2 * s]     = *reinterpret_cast<const float4*>(xn + s * 32);
                rn[2 * s + 1] = *reinterpret_cast<const float4*>(xn + s * 32 + 4);
            }
        }

        // ===== critic L1: states + next share each weight frag =====
        float4v accC[4], accN[4];
        #pragma unroll
        for (int c = 0; c < 4; ++c) {
            accC[c] = (float4v){bc1[c], bc1[c], bc1[c], bc1[c]};
            accN[c] = accC[c];
        }
        #pragma unroll
        for (int s = 0; s < 4; ++s) {
            #pragma unroll
            for (int c = 0; c < 4; ++c) {
                short8v w = spk[(FC1 + s * 4 + c) * 64 + l];
                accC[c] = __builtin_amdgcn_mfma_f32_16x16x32_bf16(sa[s], w, accC[c], 0, 0, 0);
                accN[c] = __builtin_amdgcn_mfma_f32_16x16x32_bf16(na[s], w, accN[c], 0, 0, 0);
            }
        }
        store_h(h0, accC, g, q);
        store_h(h1, accN, g, q);

        // ===== critic L2 (both) + linear head =====
        float4v c2C[4], c2N[4];
        #pragma unroll
        for (int c = 0; c < 4; ++c) {
            c2C[c] = (float4v){bc2[c], bc2[c], bc2[c], bc2[c]};
            c2N[c] = c2C[c];
        }
        #pragma unroll
        for (int s = 0; s < 2; ++s) {
            short8v aC = *reinterpret_cast<const short8v*>(&h0[q][s * 32 + g * 8]);
            short8v aN = *reinterpret_cast<const short8v*>(&h1[q][s * 32 + g * 8]);
            #pragma unroll
            for (int c = 0; c < 4; ++c) {
                short8v w = spk[(FC2 + s * 4 + c) * 64 + l];
                c2C[c] = __builtin_amdgcn_mfma_f32_16x16x32_bf16(aC, w, c2C[c], 0, 0, 0);
                c2N[c] = __builtin_amdgcn_mfma_f32_16x16x32_bf16(aN, w, c2N[c], 0, 0, 0);
            }
        }
        float vr[4] = {0.f, 0.f, 0.f, 0.f}, nr[4] = {0.f, 0.f, 0.f, 0.f};
        #pragma unroll
        for (int c = 0; c < 4; ++c) {
            #pragma unroll
            for (int r = 0; r < 4; ++r) {
                vr[r] = fmaf(fmaxf(c2C[c][r], 0.f), w3[c], vr[r]);
                nr[r] = fmaf(fmaxf(c2N[c][r], 0.f), w3[c], nr[r]);
            }
        }
        #pragma unroll
        for (int o = 1; o < 16; o <<= 1)
            #pragma unroll
            for (int r = 0; r < 4; ++r) {
                vr[r] += __shfl_xor(vr[r], o);
                nr[r] += __shfl_xor(nr[r], o);
            }
        float v[4], nv[4];
        #pragma unroll
        for (int r = 0; r < 4; ++r) { v[r] = vr[r] + cb3v; nv[r] = nr[r] + cb3v; }

        // ===== actor L1 / L2 / L3 =====
        float4v aA[4];
        #pragma unroll
        for (int c = 0; c < 4; ++c) aA[c] = (float4v){ba1[c], ba1[c], ba1[c], ba1[c]};
        #pragma unroll
        for (int s = 0; s < 4; ++s)
            #pragma unroll
            for (int c = 0; c < 4; ++c)
                aA[c] = __builtin_amdgcn_mfma_f32_16x16x32_bf16(sa[s], spk[(FA1 + s * 4 + c) * 64 + l], aA[c], 0, 0, 0);
        store_h(h0, aA, g, q);

        float4v a2[4];
        #pragma unroll
        for (int c = 0; c < 4; ++c) a2[c] = (float4v){ba2[c], ba2[c], ba2[c], ba2[c]};
        #pragma unroll
        for (int s = 0; s < 2; ++s) {
            short8v aa = *reinterpret_cast<const short8v*>(&h0[q][s * 32 + g * 8]);
            #pragma unroll
            for (int c = 0; c < 4; ++c)
                a2[c] = __builtin_amdgcn_mfma_f32_16x16x32_bf16(aa, spk[(FA2 + s * 4 + c) * 64 + l], a2[c], 0, 0, 0);
        }
        store_h(h1, a2, g, q);

        float4v a3 = (float4v){ab3q, ab3q, ab3q, ab3q};
        #pragma unroll
        for (int s = 0; s < 2; ++s) {
            short8v aa = *reinterpret_cast<const short8v*>(&h1[q][s * 32 + g * 8]);
            a3 = __builtin_amdgcn_mfma_f32_16x16x32_bf16(aa, spk[(FA3 + s) * 64 + l], a3, 0, 0, 0);
        }

        // ===== softmax over the 16 lanes of each group (action = q) =====
        float lg[4], mx[4], pe[4], se[4], tt[4], ent[4], logp[4];
        #pragma unroll
        for (int r = 0; r < 4; ++r) { lg[r] = a3[r]; mx[r] = lg[r]; }
        #pragma unroll
        for (int o = 1; o < 16; o <<= 1)
            #pragma unroll
            for (int r = 0; r < 4; ++r) mx[r] = fmaxf(mx[r], __shfl_xor(mx[r], o));
        #pragma unroll
        for (int r = 0; r < 4; ++r) {
            pe[r] = __expf(lg[r] - mx[r]);
            se[r] = pe[r];
            tt[r] = pe[r] * lg[r];
        }
        #pragma unroll
        for (int o = 1; o < 16; o <<= 1)
            #pragma unroll
            for (int r = 0; r < 4; ++r) {
                se[r] += __shfl_xor(se[r], o);
                tt[r] += __shfl_xor(tt[r], o);
            }
        const int4 av = *reinterpret_cast<const int4*>(&actions[r0 + g * 4]);
        const int act[4] = {av.x, av.y, av.z, av.w};
        #pragma unroll
        for (int r = 0; r < 4; ++r) {
            float ls = __logf(se[r]);
            ent[r] = mx[r] + ls - tt[r] / se[r];        // == -sum p*log p
            float sel = __shfl(lg[r], (l & 48) | act[r]);
            logp[r] = sel - mx[r] - ls;
        }

        // ===== epilogue: lane q==0 of each group writes its 4 rows =====
        if (q == 0) {
            const long long rb = r0 + g * 4;
            const float4 rw = *reinterpret_cast<const float4*>(&rewards[rb]);
            const float4 dn = *reinterpret_cast<const float4*>(&dones[rb]);
            const float4 ol = *reinterpret_cast<const float4*>(&old_logp[rb]);
            const float rwv[4] = {rw.x, rw.y, rw.z, rw.w};
            const float dnv[4] = {dn.x, dn.y, dn.z, dn.w};
            const float olv[4] = {ol.x, ol.y, ol.z, ol.w};
            const float GL = 0.99f * 0.95f;
            float dl[4], cf[4], rt[4];
            #pragma unroll
            for (int r = 0; r < 4; ++r) {
                float nd = 1.f - dnv[r];
                dl[r] = fmaf(0.99f * nd, nv[r], rwv[r]) - v[r];
                cf[r] = GL * nd;
                rt[r] = __expf(logp[r] - olv[r]);
            }
            float4 t;
            t.x = dl[0]; t.y = dl[1]; t.z = dl[2]; t.w = dl[3];
            *reinterpret_cast<float4*>(&delta_o[rb]) = t;
            t.x = cf[0]; t.y = cf[1]; t.z = cf[2]; t.w = cf[3];
            *reinterpret_cast<float4*>(&coef_o[rb]) = t;
            t.x = rt[0]; t.y = rt[1]; t.z = rt[2]; t.w = rt[3];
            *reinterpret_cast<float4*>(&ratio_o[rb]) = t;
            t.x = ent[0]; t.y = ent[1]; t.z = ent[2]; t.w = ent[3];
            *reinterpret_cast<float4*>(&ent_o[rb]) = t;
        }

        if (next >= NTILE) break;
        tile = next;
    }
}

// ---------------- GAE: chunk transforms ----------------
__global__ __launch_bounds__(256) void k_gae_chunk(
    const float* __restrict__ coef, const float* __restrict__ delta,
    float* __restrict__ P, float* __restrict__ Q)
{
    const int c = blockIdx.x * 256 + threadIdx.x;
    const long long lo = (long long)c * CHUNKL;
    float p = 1.f, a = 0.f;
    if (lo < T_N) {
        const int n = (int)((T_N - lo < CHUNKL) ? (T_N - lo) : CHUNKL);
        for (int j = (n >> 2) - 1; j >= 0; --j) {
            float4 cfv = *reinterpret_cast<const float4*>(&coef[lo + 4 * j]);
            float4 dlv = *reinterpret_cast<const float4*>(&delta[lo + 4 * j]);
            a = fmaf(cfv.w, a, dlv.w);
            a = fmaf(cfv.z, a, dlv.z);
            a = fmaf(cfv.y, a, dlv.y);
            a = fmaf(cfv.x, a, dlv.x);
            p *= cfv.x * cfv.y * cfv.z * cfv.w;
        }
    }
    P[c] = p; Q[c] = a;
}

// suffix scan of 4096 chunk transforms in one block (4 per thread)
__global__ __launch_bounds__(1024) void k_gae_scan(
    const float* __restrict__ P, const float* __restrict__ Q,
    float* __restrict__ carry)
{
    __shared__ float sp[1024], sq[1024];
    const int t = threadIdx.x, b = t * 4;
    float p = P[b + 3], q = Q[b + 3];
    #pragma unroll
    for (int c = 2; c >= 0; --c) {
        float pc = P[b + c], qc = Q[b + c];
        q = fmaf(pc, q, qc);
        p = pc * p;
    }
    sp[t] = p; sq[t] = q;
    __syncthreads();
    for (int d = 1; d < 1024; d <<= 1) {
        float pp = sp[t], qq = sq[t];
        float p2 = 1.f, q2 = 0.f;
        const bool has = (t + d) < 1024;
        if (has) { p2 = sp[t + d]; q2 = sq[t + d]; }
        __syncthreads();
        if (has) { sp[t] = pp * p2; sq[t] = fmaf(pp, q2, qq); }
        __syncthreads();
    }
    float x = (t + 1 < 1024) ? sq[t + 1] : 0.f;
    #pragma unroll
    for (int c = 3; c >= 0; --c) {
        carry[b + c] = x;
        x = fmaf(P[b + c], x, Q[b + c]);
    }
}

// apply carries, write adv, fused sum/sum^2 partials
__global__ __launch_bounds__(256) void k_gae_apply(
    const float* __restrict__ coef, const float* __restrict__ delta,
    const float* __restrict__ carry, float* __restrict__ adv,
    float* __restrict__ part)
{
    const int c = blockIdx.x * 256 + threadIdx.x;
    const long long lo = (long long)c * CHUNKL;
    float s = 0.f, s2 = 0.f;
    if (lo < T_N) {
        const int n = (int)((T_N - lo < CHUNKL) ? (T_N - lo) : CHUNKL);
        float a = carry[c];
        for (int j = (n >> 2) - 1; j >= 0; --j) {
            float4 cfv = *reinterpret_cast<const float4*>(&coef[lo + 4 * j]);
            float4 dlv = *reinterpret_cast<const float4*>(&delta[lo + 4 * j]);
            float a3 = fmaf(cfv.w, a, dlv.w);
            float a2v = fmaf(cfv.z, a3, dlv.z);
            float a1 = fmaf(cfv.y, a2v, dlv.y);
            float a0 = fmaf(cfv.x, a1, dlv.x);
            float4 o; o.x = a0; o.y = a1; o.z = a2v; o.w = a3;
            *reinterpret_cast<float4*>(&adv[lo + 4 * j]) = o;
            a = a0;
            s += a0 + a1 + a2v + a3;
            s2 += a0 * a0 + a1 * a1 + a2v * a2v + a3 * a3;
        }
    }
    #pragma unroll
    for (int o = 32; o > 0; o >>= 1) { s += __shfl_down(s, o); s2 += __shfl_down(s2, o); }
    __shared__ float l0[4], l1[4];
    const int wv = threadIdx.x >> 6, ln = threadIdx.x & 63;
    if (ln == 0) { l0[wv] = s; l1[wv] = s2; }
    __syncthreads();
    if (threadIdx.x == 0) {
        part[blockIdx.x * 2]     = l0[0] + l0[1] + l0[2] + l0[3];
        part[blockIdx.x * 2 + 1] = l1[0] + l1[1] + l1[2] + l1[3];
    }
}

// actor surrogate + entropy reduction
__global__ __launch_bounds__(256) void k_actor(
    const float* __restrict__ adv, const float* __restrict__ ratio,
    const float* __restrict__ ent, const float* __restrict__ part,
    float* __restrict__ part4)
{
    __shared__ float st[2];
    if (threadIdx.x == 0) {
        float S = 0.f, S2 = 0.f;
        #pragma unroll
        for (int i = 0; i < 16; ++i) { S += part[2 * i]; S2 += part[2 * i + 1]; }
        const float Tf = (float)T_N;
        float mean = S / Tf;
        float var = (S2 - S * S / Tf) / (Tf - 1.f);
        st[0] = mean;
        st[1] = 1.f / (sqrtf(fmaxf(var, 0.f)) + 1e-8f);
    }
    __syncthreads();
    const float mean = st[0], isd = st[1];
    float sm = 0.f, se = 0.f;
    for (long long i = (long long)blockIdx.x * 256 + threadIdx.x; i < T_N;
         i += (long long)gridDim.x * 256) {
        float an = (adv[i] - mean) * isd;
        float rt = ratio[i];
        float s1 = rt * an;
        float s2v = fminf(fmaxf(rt, 0.8f), 1.2f) * an;
        sm += fminf(s1, s2v);
        se += ent[i];
    }
    #pragma unroll
    for (int o = 32; o > 0; o >>= 1) { sm += __shfl_down(sm, o); se += __shfl_down(se, o); }
    __shared__ float l0[4], l1[4];
    const int wv = threadIdx.x >> 6, ln = threadIdx.x & 63;
    if (ln == 0) { l0[wv] = sm; l1[wv] = se; }
    __syncthreads();
    if (threadIdx.x == 0) {
        part4[blockIdx.x * 2]     = l0[0] + l0[1] + l0[2] + l0[3];
        part4[blockIdx.x * 2 + 1] = l1[0] + l1[1] + l1[2] + l1[3];
    }
}

__global__ __launch_bounds__(1024) void k_final(
    const float* __restrict__ part4, const float* __restrict__ part,
    float* __restrict__ out)
{
    const int t = threadIdx.x;
    float sm = part4[t * 2], se = part4[t * 2 + 1];
    #pragma unroll
    for (int o = 32; o > 0; o >>= 1) { sm += __shfl_down(sm, o); se += __shfl_down(se, o); }
    __shared__ float l0[16], l1[16];
    const int wv = t >> 6, ln = t & 63;
    if (ln == 0) { l0[wv] = sm; l1[wv] = se; }
    __syncthreads();
    if (t == 0) {
        float SM = 0.f, SE = 0.f;
        #pragma unroll
        for (int i = 0; i < 16; ++i) { SM += l0[i]; SE += l1[i]; }
        float S2 = 0.f;
        #pragma unroll
        for (int i = 0; i < 16; ++i) S2 += part[2 * i + 1];
        const float Tf = (float)T_N;
        float actor_loss = -SM / Tf;
        float ent_loss = SE / Tf;
        float critic_loss = S2 / Tf;     // mean(adv^2) == mean((v-returns)^2)
        float total = actor_loss + 0.5f * critic_loss - 0.01f * ent_loss;
        out[0] = total; out[1] = actor_loss; out[2] = critic_loss; out[3] = ent_loss;
    }
}

extern "C" void kernel_launch(void* const* d_in, const int* in_sizes, int n_in,
                              void* d_out, int out_size, void* d_ws, size_t ws_size,
                              hipStream_t stream) {
    (void)in_sizes; (void)n_in; (void)out_size; (void)ws_size;
    const float* states      = (const float*)d_in[0];
    const float* next_states = (const float*)d_in[1];
    const float* rewards     = (const float*)d_in[2];
    const float* dones       = (const float*)d_in[3];
    const int*   actions     = (const int*)d_in[4];
    const float* old_logp    = (const float*)d_in[5];
    const float* aW1 = (const float*)d_in[6];  const float* ab1 = (const float*)d_in[7];
    const float* aW2 = (const float*)d_in[8];  const float* ab2 = (const float*)d_in[9];
    const float* aW3 = (const float*)d_in[10]; const float* ab3 = (const float*)d_in[11];
    const float* cW1 = (const float*)d_in[12]; const float* cb1 = (const float*)d_in[13];
    const float* cW2 = (const float*)d_in[14]; const float* cb2 = (const float*)d_in[15];
    const float* cW3 = (const float*)d_in[16]; const float* cb3 = (const float*)d_in[17];
    float* out = (float*)d_out;

    float* ws = (float*)d_ws;
    float* delta = ws;                      // T
    float* coef  = ws + 1 * (size_t)T_N;    // T
    float* ratio = ws + 2 * (size_t)T_N;    // T
    float* entb  = ws + 3 * (size_t)T_N;    // T
    float* adv   = ws + 4 * (size_t)T_N;    // T
    float* P     = ws + 5 * (size_t)T_N;    // 4096
    float* Q     = P + NCHUNK;              // 4096
    float* carry = Q + NCHUNK;              // 4096
    float* part  = carry + NCHUNK;          // 32
    float* part4 = part + 32;               // 2048
    short8v* packed = (short8v*)(part4 + 2048);  // 50KB, 16B-aligned offset

    k_pack<<<NFRAG, 64, 0, stream>>>(cW1, aW1, cW2, aW2, aW3, packed);
    k_mlp<<<NBLK, 256, 0, stream>>>(
        states, next_states, rewards, dones, actions, old_logp, packed,
        cb1, ab1, cb2, ab2, ab3, cW3, cb3, delta, coef, ratio, entb);
    k_gae_chunk<<<NCHUNK / 256, 256, 0, stream>>>(coef, delta, P, Q);
    k_gae_scan<<<1, 1024, 0, stream>>>(P, Q, carry);
    k_gae_apply<<<NCHUNK / 256, 256, 0, stream>>>(coef, delta, carry, adv, part);
    k_actor<<<NPART, 256, 0, stream>>>(adv, ratio, entb, part, part4);
    k_final<<<1, 1024, 0, stream>>>(part4, part, out);
}

// Round 7
// 209.206 us; speedup vs baseline: 1.0787x; 1.0123x over previous
//
#include <hip/hip_runtime.h>
#include <hip/hip_bf16.h>

#define T_N 500000
#define NTILE 31250          // T_N / 16 rows per wave-tile (exact)
#define NBLK 512             // persistent blocks (2/CU at ~69KB LDS)
#define NWAVES (NBLK * 4)    // wave stride over tiles
#define NCHUNK 4096
#define CHUNKL 128
#define NPART 1024

typedef __attribute__((ext_vector_type(8))) short short8v;
typedef __attribute__((ext_vector_type(4))) float float4v;

__device__ __forceinline__ short f2bf(float f) {
    __hip_bfloat16 b = __float2bfloat16(f);
    return *reinterpret_cast<short*>(&b);
}
__device__ __forceinline__ float bf2f(short s) {
    return __uint_as_float(((unsigned)(unsigned short)s) << 16);
}

__device__ __forceinline__ short8v cvt8(const float4 a, const float4 b) {
    short8v r;
    r[0] = f2bf(a.x); r[1] = f2bf(a.y); r[2] = f2bf(a.z); r[3] = f2bf(a.w);
    r[4] = f2bf(b.x); r[5] = f2bf(b.y); r[6] = f2bf(b.z); r[7] = f2bf(b.w);
    return r;
}

// packed B-fragment base indices (each frag = 64 lanes x 8 bf16 = 1KB)
#define FC1 0    // critic W1: 4 k-steps x 4 col-tiles
#define FA1 16   // actor  W1
#define FC2 32   // critic W2: 2 k-steps x 4 col-tiles
#define FA2 40   // actor  W2
#define FA3 48   // actor  W3: 2 k-steps x 1 col-tile (16 actions)
#define NFRAG 50

// ---- weight pre-pack: B-frag slot (g=lane>>4, j) <-> k = s*32 + g*8 + j ----
__global__ __launch_bounds__(64) void k_pack(
    const float* __restrict__ cW1, const float* __restrict__ aW1,
    const float* __restrict__ cW2, const float* __restrict__ aW2,
    const float* __restrict__ aW3, short8v* __restrict__ packed)
{
    const int f = blockIdx.x, l = threadIdx.x;
    const int g = l >> 4, col = l & 15;
    const float* W; int s, c, ncol;
    if (f < FA1)      { W = cW1; s = f >> 2;         c = f & 3;         ncol = 64; }
    else if (f < FC2) { W = aW1; s = (f - FA1) >> 2; c = (f - FA1) & 3; ncol = 64; }
    else if (f < FA2) { W = cW2; s = (f - FC2) >> 2; c = (f - FC2) & 3; ncol = 64; }
    else if (f < FA3) { W = aW2; s = (f - FA2) >> 2; c = (f - FA2) & 3; ncol = 64; }
    else              { W = aW3; s = f - FA3;        c = 0;             ncol = 16; }
    short8v frag;
    #pragma unroll
    for (int j = 0; j < 8; ++j) {
        int k = s * 32 + g * 8 + j;
        frag[j] = f2bf(W[k * ncol + c * 16 + col]);
    }
    packed[f * 64 + l] = frag;
}

__device__ __forceinline__ void store_h(short (*hb)[68], const float4v* acc, int g, int q) {
    #pragma unroll
    for (int c = 0; c < 4; ++c)
        #pragma unroll
        for (int r = 0; r < 4; ++r)
            hb[g * 4 + r][c * 16 + q] = f2bf(fmaxf(acc[c][r], 0.f));
}

// ---- persistent pure-GEMM MLP: writes v, nv (f32) + logits (bf16) only ----
__global__ __launch_bounds__(256) void k_mlp(
    const float* __restrict__ states, const float* __restrict__ next_states,
    const short8v* __restrict__ pk,
    const float* __restrict__ cb1, const float* __restrict__ ab1,
    const float* __restrict__ cb2, const float* __restrict__ ab2,
    const float* __restrict__ ab3,
    const float* __restrict__ cW3, const float* __restrict__ cb3,
    float* __restrict__ v_o, float* __restrict__ nv_o,
    short* __restrict__ logit_o)
{
    __shared__ __align__(16) short8v spk[NFRAG * 64];     // 51.2 KB weights
    __shared__ __align__(16) short hlds[4][2][16][68];    // 17.4 KB h buffers
    const int wv = threadIdx.x >> 6, l = threadIdx.x & 63;
    const int g = l >> 4, q = l & 15;
    short (*h0)[68] = hlds[wv][0];
    short (*h1)[68] = hlds[wv][1];

    for (int i = threadIdx.x; i < NFRAG * 64; i += 256) spk[i] = pk[i];
    __syncthreads();                                       // only barrier

    int tile = blockIdx.x * 4 + wv;
    if (tile >= NTILE) return;

    float bc1[4], bc2[4], ba1[4], ba2[4], w3[4];
    #pragma unroll
    for (int c = 0; c < 4; ++c) {
        bc1[c] = cb1[c * 16 + q];
        bc2[c] = cb2[c * 16 + q];
        ba1[c] = ab1[c * 16 + q];
        ba2[c] = ab2[c * 16 + q];
        w3[c]  = cW3[c * 16 + q];
    }
    const float ab3q = ab3[q];
    const float cb3v = cb3[0];

    float4 rs[8], rn[8];
    {
        const float* xs = states + ((long long)tile * 16 + q) * 128 + g * 8;
        const float* xn = next_states + ((long long)tile * 16 + q) * 128 + g * 8;
        #pragma unroll
        for (int s = 0; s < 4; ++s) {
            rs[2 * s]     = *reinterpret_cast<const float4*>(xs + s * 32);
            rs[2 * s + 1] = *reinterpret_cast<const float4*>(xs + s * 32 + 4);
            rn[2 * s]     = *reinterpret_cast<const float4*>(xn + s * 32);
            rn[2 * s + 1] = *reinterpret_cast<const float4*>(xn + s * 32 + 4);
        }
    }

    while (true) {
        const int next = tile + NWAVES;
        const long long r0 = (long long)tile * 16;

        short8v sa[4], na[4];
        #pragma unroll
        for (int s = 0; s < 4; ++s) {
            sa[s] = cvt8(rs[2 * s], rs[2 * s + 1]);
            na[s] = cvt8(rn[2 * s], rn[2 * s + 1]);
        }

        if (next < NTILE) {
            const float* xs = states + ((long long)next * 16 + q) * 128 + g * 8;
            const float* xn = next_states + ((long long)next * 16 + q) * 128 + g * 8;
            #pragma unroll
            for (int s = 0; s < 4; ++s) {
                rs[2 * s]     = *reinterpret_cast<const float4*>(xs + s * 32);
                rs[2 * s + 1] = *reinterpret_cast<const float4*>(xs + s * 32 + 4);
                rn[2 * s]     = *reinterpret_cast<const float4*>(xn + s * 32);
                rn[2 * s + 1] = *reinterpret_cast<const float4*>(xn + s * 32 + 4);
            }
        }

        // ===== critic L1: states + next share each weight frag =====
        float4v accC[4], accN[4];
        #pragma unroll
        for (int c = 0; c < 4; ++c) {
            accC[c] = (float4v){bc1[c], bc1[c], bc1[c], bc1[c]};
            accN[c] = accC[c];
        }
        #pragma unroll
        for (int s = 0; s < 4; ++s) {
            #pragma unroll
            for (int c = 0; c < 4; ++c) {
                short8v w = spk[(FC1 + s * 4 + c) * 64 + l];
                accC[c] = __builtin_amdgcn_mfma_f32_16x16x32_bf16(sa[s], w, accC[c], 0, 0, 0);
                accN[c] = __builtin_amdgcn_mfma_f32_16x16x32_bf16(na[s], w, accN[c], 0, 0, 0);
            }
        }
        store_h(h0, accC, g, q);
        store_h(h1, accN, g, q);

        // ===== critic L2 (both) + linear head via shfl reduce =====
        float4v c2C[4], c2N[4];
        #pragma unroll
        for (int c = 0; c < 4; ++c) {
            c2C[c] = (float4v){bc2[c], bc2[c], bc2[c], bc2[c]};
            c2N[c] = c2C[c];
        }
        #pragma unroll
        for (int s = 0; s < 2; ++s) {
            short8v aC = *reinterpret_cast<const short8v*>(&h0[q][s * 32 + g * 8]);
            short8v aN = *reinterpret_cast<const short8v*>(&h1[q][s * 32 + g * 8]);
            #pragma unroll
            for (int c = 0; c < 4; ++c) {
                short8v w = spk[(FC2 + s * 4 + c) * 64 + l];
                c2C[c] = __builtin_amdgcn_mfma_f32_16x16x32_bf16(aC, w, c2C[c], 0, 0, 0);
                c2N[c] = __builtin_amdgcn_mfma_f32_16x16x32_bf16(aN, w, c2N[c], 0, 0, 0);
            }
        }
        float vr[4] = {0.f, 0.f, 0.f, 0.f}, nr[4] = {0.f, 0.f, 0.f, 0.f};
        #pragma unroll
        for (int c = 0; c < 4; ++c) {
            #pragma unroll
            for (int r = 0; r < 4; ++r) {
                vr[r] = fmaf(fmaxf(c2C[c][r], 0.f), w3[c], vr[r]);
                nr[r] = fmaf(fmaxf(c2N[c][r], 0.f), w3[c], nr[r]);
            }
        }
        #pragma unroll
        for (int o = 1; o < 16; o <<= 1)
            #pragma unroll
            for (int r = 0; r < 4; ++r) {
                vr[r] += __shfl_xor(vr[r], o);
                nr[r] += __shfl_xor(nr[r], o);
            }
        if (q == 0) {
            float4 tv, tn;
            tv.x = vr[0] + cb3v; tv.y = vr[1] + cb3v; tv.z = vr[2] + cb3v; tv.w = vr[3] + cb3v;
            tn.x = nr[0] + cb3v; tn.y = nr[1] + cb3v; tn.z = nr[2] + cb3v; tn.w = nr[3] + cb3v;
            *reinterpret_cast<float4*>(&v_o[r0 + g * 4])  = tv;
            *reinterpret_cast<float4*>(&nv_o[r0 + g * 4]) = tn;
        }

        // ===== actor L1 / L2 / L3 =====
        float4v aA[4];
        #pragma unroll
        for (int c = 0; c < 4; ++c) aA[c] = (float4v){ba1[c], ba1[c], ba1[c], ba1[c]};
        #pragma unroll
        for (int s = 0; s < 4; ++s)
            #pragma unroll
            for (int c = 0; c < 4; ++c)
                aA[c] = __builtin_amdgcn_mfma_f32_16x16x32_bf16(sa[s], spk[(FA1 + s * 4 + c) * 64 + l], aA[c], 0, 0, 0);
        store_h(h0, aA, g, q);

        float4v a2[4];
        #pragma unroll
        for (int c = 0; c < 4; ++c) a2[c] = (float4v){ba2[c], ba2[c], ba2[c], ba2[c]};
        #pragma unroll
        for (int s = 0; s < 2; ++s) {
            short8v aa = *reinterpret_cast<const short8v*>(&h0[q][s * 32 + g * 8]);
            #pragma unroll
            for (int c = 0; c < 4; ++c)
                a2[c] = __builtin_amdgcn_mfma_f32_16x16x32_bf16(aa, spk[(FA2 + s * 4 + c) * 64 + l], a2[c], 0, 0, 0);
        }
        store_h(h1, a2, g, q);

        float4v a3 = (float4v){ab3q, ab3q, ab3q, ab3q};
        #pragma unroll
        for (int s = 0; s < 2; ++s) {
            short8v aa = *reinterpret_cast<const short8v*>(&h1[q][s * 32 + g * 8]);
            a3 = __builtin_amdgcn_mfma_f32_16x16x32_bf16(aa, spk[(FA3 + s) * 64 + l], a3, 0, 0, 0);
        }
        // logits out (bf16): lane (g,q) holds rows g*4+r, action col q
        #pragma unroll
        for (int r = 0; r < 4; ++r)
            logit_o[(r0 + g * 4 + r) * 16 + q] = f2bf(a3[r]);

        if (next >= NTILE) break;
        tile = next;
    }
}

// ---------------- GAE chunk: delta/coef on the fly ----------------
__device__ __forceinline__ void dc_elem(float v, float nv, float rw, float dn,
                                        float& d, float& c) {
    float nd = 1.f - dn;
    d = fmaf(0.99f * nd, nv, rw) - v;
    c = (0.99f * 0.95f) * nd;
}

__global__ __launch_bounds__(256) void k_gae_chunk(
    const float* __restrict__ v_i, const float* __restrict__ nv_i,
    const float* __restrict__ rewards, const float* __restrict__ dones,
    float* __restrict__ P, float* __restrict__ Q)
{
    const int c = blockIdx.x * 256 + threadIdx.x;
    const long long lo = (long long)c * CHUNKL;
    float p = 1.f, a = 0.f;
    if (lo < T_N) {
        const int n = (int)((T_N - lo < CHUNKL) ? (T_N - lo) : CHUNKL);
        for (int j = (n >> 2) - 1; j >= 0; --j) {
            float4 vv = *reinterpret_cast<const float4*>(&v_i[lo + 4 * j]);
            float4 nn = *reinterpret_cast<const float4*>(&nv_i[lo + 4 * j]);
            float4 rw = *reinterpret_cast<const float4*>(&rewards[lo + 4 * j]);
            float4 dn = *reinterpret_cast<const float4*>(&dones[lo + 4 * j]);
            float d0, c0, d1, c1, d2, c2, d3, c3;
            dc_elem(vv.x, nn.x, rw.x, dn.x, d0, c0);
            dc_elem(vv.y, nn.y, rw.y, dn.y, d1, c1);
            dc_elem(vv.z, nn.z, rw.z, dn.z, d2, c2);
            dc_elem(vv.w, nn.w, rw.w, dn.w, d3, c3);
            a = fmaf(c3, a, d3);
            a = fmaf(c2, a, d2);
            a = fmaf(c1, a, d1);
            a = fmaf(c0, a, d0);
            p *= c0 * c1 * c2 * c3;
        }
    }
    P[c] = p; Q[c] = a;
}

// suffix scan of 4096 chunk transforms in one block (4 per thread)
__global__ __launch_bounds__(1024) void k_gae_scan(
    const float* __restrict__ P, const float* __restrict__ Q,
    float* __restrict__ carry)
{
    __shared__ float sp[1024], sq[1024];
    const int t = threadIdx.x, b = t * 4;
    float p = P[b + 3], q = Q[b + 3];
    #pragma unroll
    for (int c = 2; c >= 0; --c) {
        float pc = P[b + c], qc = Q[b + c];
        q = fmaf(pc, q, qc);
        p = pc * p;
    }
    sp[t] = p; sq[t] = q;
    __syncthreads();
    for (int d = 1; d < 1024; d <<= 1) {
        float pp = sp[t], qq = sq[t];
        float p2 = 1.f, q2 = 0.f;
        const bool has = (t + d) < 1024;
        if (has) { p2 = sp[t + d]; q2 = sq[t + d]; }
        __syncthreads();
        if (has) { sp[t] = pp * p2; sq[t] = fmaf(pp, q2, qq); }
        __syncthreads();
    }
    float x = (t + 1 < 1024) ? sq[t + 1] : 0.f;
    #pragma unroll
    for (int c = 3; c >= 0; --c) {
        carry[b + c] = x;
        x = fmaf(P[b + c], x, Q[b + c]);
    }
}

// apply carries (recompute delta/coef), write adv, fused sum/sum^2 partials
__global__ __launch_bounds__(256) void k_gae_apply(
    const float* __restrict__ v_i, const float* __restrict__ nv_i,
    const float* __restrict__ rewards, const float* __restrict__ dones,
    const float* __restrict__ carry, float* __restrict__ adv,
    float* __restrict__ part)
{
    const int c = blockIdx.x * 256 + threadIdx.x;
    const long long lo = (long long)c * CHUNKL;
    float s = 0.f, s2 = 0.f;
    if (lo < T_N) {
        const int n = (int)((T_N - lo < CHUNKL) ? (T_N - lo) : CHUNKL);
        float a = carry[c];
        for (int j = (n >> 2) - 1; j >= 0; --j) {
            float4 vv = *reinterpret_cast<const float4*>(&v_i[lo + 4 * j]);
            float4 nn = *reinterpret_cast<const float4*>(&nv_i[lo + 4 * j]);
            float4 rw = *reinterpret_cast<const float4*>(&rewards[lo + 4 * j]);
            float4 dn = *reinterpret_cast<const float4*>(&dones[lo + 4 * j]);
            float d0, c0, d1, c1, d2, c2, d3, c3;
            dc_elem(vv.x, nn.x, rw.x, dn.x, d0, c0);
            dc_elem(vv.y, nn.y, rw.y, dn.y, d1, c1);
            dc_elem(vv.z, nn.z, rw.z, dn.z, d2, c2);
            dc_elem(vv.w, nn.w, rw.w, dn.w, d3, c3);
            float a3 = fmaf(c3, a, d3);
            float a2v = fmaf(c2, a3, d2);
            float a1 = fmaf(c1, a2v, d1);
            float a0 = fmaf(c0, a1, d0);
            float4 o; o.x = a0; o.y = a1; o.z = a2v; o.w = a3;
            *reinterpret_cast<float4*>(&adv[lo + 4 * j]) = o;
            a = a0;
            s += a0 + a1 + a2v + a3;
            s2 += a0 * a0 + a1 * a1 + a2v * a2v + a3 * a3;
        }
    }
    #pragma unroll
    for (int o = 32; o > 0; o >>= 1) { s += __shfl_down(s, o); s2 += __shfl_down(s2, o); }
    __shared__ float l0[4], l1[4];
    const int wv = threadIdx.x >> 6, ln = threadIdx.x & 63;
    if (ln == 0) { l0[wv] = s; l1[wv] = s2; }
    __syncthreads();
    if (threadIdx.x == 0) {
        part[blockIdx.x * 2]     = l0[0] + l0[1] + l0[2] + l0[3];
        part[blockIdx.x * 2 + 1] = l1[0] + l1[1] + l1[2] + l1[3];
    }
}

// per-row in-lane softmax + surrogate + entropy reduction
__global__ __launch_bounds__(256) void k_actor(
    const float* __restrict__ adv, const short* __restrict__ logits,
    const float* __restrict__ old_logp, const int* __restrict__ actions,
    const float* __restrict__ part, float* __restrict__ part4)
{
    __shared__ float st[2];
    if (threadIdx.x == 0) {
        float S = 0.f, S2 = 0.f;
        #pragma unroll
        for (int i = 0; i < 16; ++i) { S += part[2 * i]; S2 += part[2 * i + 1]; }
        const float Tf = (float)T_N;
        float mean = S / Tf;
        float var = (S2 - S * S / Tf) / (Tf - 1.f);
        st[0] = mean;
        st[1] = 1.f / (sqrtf(fmaxf(var, 0.f)) + 1e-8f);
    }
    __syncthreads();
    const float mean = st[0], isd = st[1];
    float sm = 0.f, sent = 0.f;
    for (long long i = (long long)blockIdx.x * 256 + threadIdx.x; i < T_N;
         i += (long long)gridDim.x * 256) {
        const short8v* lp = reinterpret_cast<const short8v*>(logits) + i * 2;
        short8v lo0 = lp[0], lo1 = lp[1];
        float lg[16];
        #pragma unroll
        for (int j = 0; j < 8; ++j) { lg[j] = bf2f(lo0[j]); lg[8 + j] = bf2f(lo1[j]); }
        float m = lg[0];
        #pragma unroll
        for (int a = 1; a < 16; ++a) m = fmaxf(m, lg[a]);
        float se = 0.f, tt = 0.f;
        #pragma unroll
        for (int a = 0; a < 16; ++a) {
            float e = __expf(lg[a] - m);
            se += e;
            tt = fmaf(e, lg[a], tt);
        }
        float ls = __logf(se);
        float ent = m + ls - tt / se;
        const int act = actions[i];
        float lsel = lg[0];
        #pragma unroll
        for (int a = 1; a < 16; ++a) lsel = (a == act) ? lg[a] : lsel;
        float logp = lsel - m - ls;
        float rt = __expf(logp - old_logp[i]);
        float an = (adv[i] - mean) * isd;
        sm += fminf(rt * an, fminf(fmaxf(rt, 0.8f), 1.2f) * an);
        sent += ent;
    }
    #pragma unroll
    for (int o = 32; o > 0; o >>= 1) { sm += __shfl_down(sm, o); sent += __shfl_down(sent, o); }
    __shared__ float l0[4], l1[4];
    const int wv = threadIdx.x >> 6, ln = threadIdx.x & 63;
    if (ln == 0) { l0[wv] = sm; l1[wv] = sent; }
    __syncthreads();
    if (threadIdx.x == 0) {
        part4[blockIdx.x * 2]     = l0[0] + l0[1] + l0[2] + l0[3];
        part4[blockIdx.x * 2 + 1] = l1[0] + l1[1] + l1[2] + l1[3];
    }
}

__global__ __launch_bounds__(1024) void k_final(
    const float* __restrict__ part4, const float* __restrict__ part,
    float* __restrict__ out)
{
    const int t = threadIdx.x;
    float sm = part4[t * 2], se = part4[t * 2 + 1];
    #pragma unroll
    for (int o = 32; o > 0; o >>= 1) { sm += __shfl_down(sm, o); se += __shfl_down(se, o); }
    __shared__ float l0[16], l1[16];
    const int wv = t >> 6, ln = t & 63;
    if (ln == 0) { l0[wv] = sm; l1[wv] = se; }
    __syncthreads();
    if (t == 0) {
        float SM = 0.f, SE = 0.f;
        #pragma unroll
        for (int i = 0; i < 16; ++i) { SM += l0[i]; SE += l1[i]; }
        float S2 = 0.f;
        #pragma unroll
        for (int i = 0; i < 16; ++i) S2 += part[2 * i + 1];
        const float Tf = (float)T_N;
        float actor_loss = -SM / Tf;
        float ent_loss = SE / Tf;
        float critic_loss = S2 / Tf;     // mean(adv^2) == mean((v-returns)^2)
        float total = actor_loss + 0.5f * critic_loss - 0.01f * ent_loss;
        out[0] = total; out[1] = actor_loss; out[2] = critic_loss; out[3] = ent_loss;
    }
}

extern "C" void kernel_launch(void* const* d_in, const int* in_sizes, int n_in,
                              void* d_out, int out_size, void* d_ws, size_t ws_size,
                              hipStream_t stream) {
    (void)in_sizes; (void)n_in; (void)out_size; (void)ws_size;
    const float* states      = (const float*)d_in[0];
    const float* next_states = (const float*)d_in[1];
    const float* rewards     = (const float*)d_in[2];
    const float* dones       = (const float*)d_in[3];
    const int*   actions     = (const int*)d_in[4];
    const float* old_logp    = (const float*)d_in[5];
    const float* aW1 = (const float*)d_in[6];  const float* ab1 = (const float*)d_in[7];
    const float* aW2 = (const float*)d_in[8];  const float* ab2 = (const float*)d_in[9];
    const float* aW3 = (const float*)d_in[10]; const float* ab3 = (const float*)d_in[11];
    const float* cW1 = (const float*)d_in[12]; const float* cb1 = (const float*)d_in[13];
    const float* cW2 = (const float*)d_in[14]; const float* cb2 = (const float*)d_in[15];
    const float* cW3 = (const float*)d_in[16]; const float* cb3 = (const float*)d_in[17];
    float* out = (float*)d_out;

    // ws layout: logits (bf16, T*16) first for 16B alignment, then floats
    short* logits = (short*)d_ws;                           // 16 MB
    float* fbase = (float*)(logits + (size_t)T_N * 16);
    float* v_ws  = fbase;                                   // T
    float* nv_ws = fbase + (size_t)T_N;                     // T
    float* adv   = fbase + 2 * (size_t)T_N;                 // T
    float* P     = fbase + 3 * (size_t)T_N;                 // 4096
    float* Q     = P + NCHUNK;                              // 4096
    float* carry = Q + NCHUNK;                              // 4096
    float* part  = carry + NCHUNK;                          // 32
    float* part4 = part + 32;                               // 2048
    short8v* packed = (short8v*)(part4 + 2048);             // 50KB

    k_pack<<<NFRAG, 64, 0, stream>>>(cW1, aW1, cW2, aW2, aW3, packed);
    k_mlp<<<NBLK, 256, 0, stream>>>(
        states, next_states, packed,
        cb1, ab1, cb2, ab2, ab3, cW3, cb3, v_ws, nv_ws, logits);
    k_gae_chunk<<<NCHUNK / 256, 256, 0, stream>>>(v_ws, nv_ws, rewards, dones, P, Q);
    k_gae_scan<<<1, 1024, 0, stream>>>(P, Q, carry);
    k_gae_apply<<<NCHUNK / 256, 256, 0, stream>>>(v_ws, nv_ws, rewards, dones, carry, adv, part);
    k_actor<<<NPART, 256, 0, stream>>>(adv, logits, old_logp, actions, part, part4);
    k_final<<<1, 1024, 0, stream>>>(part4, part, out);
}